// Round 7
// baseline (161.913 us; speedup 1.0000x reference)
//
#include <hip/hip_runtime.h>
#include <hip/hip_bf16.h>

#define S_ 64
#define P_ 2048
#define C_ 32
#define A_ 2048
#define D_ 128
#define E_ 64

#define LPX   64             // pixels per fused block
#define NLCH  (P_ / LPX)     // 32 chunks per scene

// ---------------------------------------------------------------------------
// att2[a,e] = de[a,:] @ W_df + b_df, plus scene-bucket scatter (fused).
// ---------------------------------------------------------------------------
__global__ __launch_bounds__(256) void att2s_kernel(
    const float* __restrict__ de, const float* __restrict__ Wdf,
    const float* __restrict__ bdf, const int* __restrict__ sidx,
    float* __restrict__ att2, int* __restrict__ counts,
    int* __restrict__ lists) {
  __shared__ float4 Wl[128 * 16];
  __shared__ float4 bl[16];
  __shared__ float  dl[16 * 128];
  const int tid = threadIdx.x;

  // scatter for this block's 16 agents
  if (tid < 16) {
    const int a = blockIdx.x * 16 + tid;
    const int s = sidx[a];
    const int pos = atomicAdd(&counts[s], 1);
    lists[s * A_ + pos] = a;
  }

  const float4* W4 = (const float4*)Wdf;
#pragma unroll
  for (int i = 0; i < 8; ++i) Wl[tid + i * 256] = W4[tid + i * 256];
  if (tid < 16) bl[tid] = ((const float4*)bdf)[tid];
  const long base = (long)blockIdx.x * (16 * 128);
#pragma unroll
  for (int i = 0; i < 8; ++i) dl[tid + i * 256] = de[base + tid + i * 256];
  __syncthreads();

  const int r = tid >> 4, e4 = tid & 15;
  float4 acc = bl[e4];
#pragma unroll 4
  for (int d = 0; d < 128; ++d) {
    const float  g = dl[r * 128 + d];
    const float4 w = Wl[d * 16 + e4];
    acc.x = fmaf(g, w.x, acc.x);
    acc.y = fmaf(g, w.y, acc.y);
    acc.z = fmaf(g, w.z, acc.z);
    acc.w = fmaf(g, w.w, acc.w);
  }
  ((float4*)att2)[((long)blockIdx.x * 16 + r) * 16 + e4] = acc;
}

// ---------------------------------------------------------------------------
// Fused logits + unnormalized softmax + pooling.
// Block = (scene, 64-px chunk). Phase 1 (per 32-agent group): lane =
// (px = tid>>2, eq = tid&3) computes l[a,px] split over 4 e-quarters
// (R6's proven loop) and stores exp(l) into alpha_l (no max subtraction:
// |l| <~ 10 for this problem since |w_fc| <= 1/8). Phase 2: remap to
// (j = tid>>3, c4 = tid&7), pool against the LDS-resident gs chunk,
// atomicAdd partial pools into out[] and partial sums into Z[].
// ---------------------------------------------------------------------------
__global__ __launch_bounds__(256) void fused_kernel(
    const float* __restrict__ gs, const float* __restrict__ Wsn,
    const float* __restrict__ bsn, const float* __restrict__ wfc,
    const float* __restrict__ att2, const int* __restrict__ counts,
    const int* __restrict__ lists, float* __restrict__ out,
    float* __restrict__ Z) {
  const int s   = blockIdx.x >> 5;
  const int p0  = (blockIdx.x & (NLCH - 1)) * LPX;
  const int tid = threadIdx.x;
  const int px  = tid >> 2;          // 0..63
  const int eq  = tid & 3;           // e-quarter

  __shared__ float  gsl[LPX][36];    // 9.2 KB; rows 144 B (16B-aligned)
  __shared__ float4 Wl4[32 * 16];    // 8 KB
  __shared__ float4 a2l[32][16];     // 2 KB
  __shared__ float  alpha_l[32][64]; // 8 KB, exp(logit) per (agent, px)
  __shared__ int    aidl[32];

  // stage W_sn
  const float4* W4 = (const float4*)Wsn;
  Wl4[tid]       = W4[tid];
  Wl4[tid + 256] = W4[tid + 256];

  // stage gs chunk: 64 px x 32 c = 512 float4, into stride-36 rows
  const float4* g4 = (const float4*)(gs + ((long)s * P_ + p0) * C_);
#pragma unroll
  for (int k = 0; k < 2; ++k) {
    const int f = tid + k * 256;
    const float4 v = g4[f];
    const int pp = f >> 3, c0 = (f & 7) * 4;
    gsl[pp][c0]     = v.x;
    gsl[pp][c0 + 1] = v.y;
    gsl[pp][c0 + 2] = v.z;
    gsl[pp][c0 + 3] = v.w;
  }

  // per-lane w_fc quads and bias-initialized att1 accumulator
  const float4* wf4 = (const float4*)wfc;
  const float4* b4  = (const float4*)bsn;
  float4 wf[4], a1[4];
#pragma unroll
  for (int q = 0; q < 4; ++q) { wf[q] = wf4[eq * 4 + q]; a1[q] = b4[eq * 4 + q]; }
  __syncthreads();

  // att1 for (pixel px, this lane's 16 e's): 32c fma (once per block)
#pragma unroll
  for (int c = 0; c < 32; ++c) {
    const float g = gsl[px][c];
#pragma unroll
    for (int q = 0; q < 4; ++q) {
      const float4 w = Wl4[c * 16 + eq * 4 + q];
      a1[q].x = fmaf(g, w.x, a1[q].x);
      a1[q].y = fmaf(g, w.y, a1[q].y);
      a1[q].z = fmaf(g, w.z, a1[q].z);
      a1[q].w = fmaf(g, w.w, a1[q].w);
    }
  }

  const int j2 = tid >> 3;           // phase-2 agent slot
  const int c4 = tid & 7;            // phase-2 channel quad
  const int n_s = counts[s];

  for (int g0 = 0; g0 < n_s; g0 += 32) {
    const int m = min(32, n_s - g0);
    __syncthreads();                 // prev group's a2l/alpha_l reads done
    if (tid < m) aidl[tid] = lists[s * A_ + g0 + tid];
    __syncthreads();
#pragma unroll
    for (int k = 0; k < 2; ++k) {
      const int idx = tid + k * 256; // 0..511
      const int j = idx >> 4, e4 = idx & 15;
      if (j < m) a2l[j][e4] = ((const float4*)att2)[aidl[j] * 16 + e4];
    }
    __syncthreads();

    // ---- phase 1: logits -> exp -> alpha_l ----
    for (int j = 0; j < m; ++j) {
      const float4 t0 = a2l[j][eq * 4 + 0];
      const float4 t1 = a2l[j][eq * 4 + 1];
      const float4 t2 = a2l[j][eq * 4 + 2];
      const float4 t3 = a2l[j][eq * 4 + 3];
      float c0 = 0.f, c1 = 0.f, c2 = 0.f, c3 = 0.f;
      c0 = fmaf(fmaxf(a1[0].x + t0.x, 0.f), wf[0].x, c0);
      c1 = fmaf(fmaxf(a1[0].y + t0.y, 0.f), wf[0].y, c1);
      c2 = fmaf(fmaxf(a1[0].z + t0.z, 0.f), wf[0].z, c2);
      c3 = fmaf(fmaxf(a1[0].w + t0.w, 0.f), wf[0].w, c3);
      c0 = fmaf(fmaxf(a1[1].x + t1.x, 0.f), wf[1].x, c0);
      c1 = fmaf(fmaxf(a1[1].y + t1.y, 0.f), wf[1].y, c1);
      c2 = fmaf(fmaxf(a1[1].z + t1.z, 0.f), wf[1].z, c2);
      c3 = fmaf(fmaxf(a1[1].w + t1.w, 0.f), wf[1].w, c3);
      c0 = fmaf(fmaxf(a1[2].x + t2.x, 0.f), wf[2].x, c0);
      c1 = fmaf(fmaxf(a1[2].y + t2.y, 0.f), wf[2].y, c1);
      c2 = fmaf(fmaxf(a1[2].z + t2.z, 0.f), wf[2].z, c2);
      c3 = fmaf(fmaxf(a1[2].w + t2.w, 0.f), wf[2].w, c3);
      c0 = fmaf(fmaxf(a1[3].x + t3.x, 0.f), wf[3].x, c0);
      c1 = fmaf(fmaxf(a1[3].y + t3.y, 0.f), wf[3].y, c1);
      c2 = fmaf(fmaxf(a1[3].z + t3.z, 0.f), wf[3].z, c2);
      c3 = fmaf(fmaxf(a1[3].w + t3.w, 0.f), wf[3].w, c3);
      float r = (c0 + c1) + (c2 + c3);
      r += __shfl_xor(r, 1);
      r += __shfl_xor(r, 2);
      if (eq == 0) alpha_l[j][px] = __expf(r);
    }
    __syncthreads();

    // ---- phase 2: pool this group against LDS-resident gs chunk ----
    if (j2 < m) {
      const int a = aidl[j2];
      float4 a0 = make_float4(0.f, 0.f, 0.f, 0.f);
      float4 a1p = make_float4(0.f, 0.f, 0.f, 0.f);
      float4 a2p = make_float4(0.f, 0.f, 0.f, 0.f);
      float4 a3p = make_float4(0.f, 0.f, 0.f, 0.f);
      float  zs = 0.f;
#pragma unroll 4
      for (int p4 = 0; p4 < LPX / 4; ++p4) {
        const float w0 = alpha_l[j2][p4 * 4 + 0];
        const float w1 = alpha_l[j2][p4 * 4 + 1];
        const float w2 = alpha_l[j2][p4 * 4 + 2];
        const float w3 = alpha_l[j2][p4 * 4 + 3];
        const float4 v0 = *(const float4*)&gsl[p4 * 4 + 0][c4 * 4];
        const float4 v1 = *(const float4*)&gsl[p4 * 4 + 1][c4 * 4];
        const float4 v2 = *(const float4*)&gsl[p4 * 4 + 2][c4 * 4];
        const float4 v3 = *(const float4*)&gsl[p4 * 4 + 3][c4 * 4];
        zs += (w0 + w1) + (w2 + w3);
        a0.x = fmaf(w0, v0.x, a0.x); a0.y = fmaf(w0, v0.y, a0.y);
        a0.z = fmaf(w0, v0.z, a0.z); a0.w = fmaf(w0, v0.w, a0.w);
        a1p.x = fmaf(w1, v1.x, a1p.x); a1p.y = fmaf(w1, v1.y, a1p.y);
        a1p.z = fmaf(w1, v1.z, a1p.z); a1p.w = fmaf(w1, v1.w, a1p.w);
        a2p.x = fmaf(w2, v2.x, a2p.x); a2p.y = fmaf(w2, v2.y, a2p.y);
        a2p.z = fmaf(w2, v2.z, a2p.z); a2p.w = fmaf(w2, v2.w, a2p.w);
        a3p.x = fmaf(w3, v3.x, a3p.x); a3p.y = fmaf(w3, v3.y, a3p.y);
        a3p.z = fmaf(w3, v3.z, a3p.z); a3p.w = fmaf(w3, v3.w, a3p.w);
      }
      const float4 acc = make_float4((a0.x + a1p.x) + (a2p.x + a3p.x),
                                     (a0.y + a1p.y) + (a2p.y + a3p.y),
                                     (a0.z + a1p.z) + (a2p.z + a3p.z),
                                     (a0.w + a1p.w) + (a2p.w + a3p.w));
      float* op = out + (long)a * C_ + c4 * 4;
      atomicAdd(op,     acc.x);
      atomicAdd(op + 1, acc.y);
      atomicAdd(op + 2, acc.z);
      atomicAdd(op + 3, acc.w);
      if (c4 == 0) atomicAdd(&Z[a], zs);
    }
  }
}

// ---------------------------------------------------------------------------
// out[a,c] /= Z[a]
// ---------------------------------------------------------------------------
__global__ __launch_bounds__(256) void norm_kernel(
    float* __restrict__ out, const float* __restrict__ Z) {
  const int i = blockIdx.x * 256 + threadIdx.x;
  out[i] = out[i] / Z[i >> 5];
}

// ---------------------------------------------------------------------------
extern "C" void kernel_launch(void* const* d_in, const int* in_sizes, int n_in,
                              void* d_out, int out_size, void* d_ws, size_t ws_size,
                              hipStream_t stream) {
  const float* gs   = (const float*)d_in[0];  // [S,P,C]
  const int*   sidx = (const int*)  d_in[1];  // [A]
  const float* de   = (const float*)d_in[2];  // [A,D]
  const float* Wsn  = (const float*)d_in[3];  // [C,E]
  const float* bsn  = (const float*)d_in[4];  // [E]
  const float* Wdf  = (const float*)d_in[5];  // [D,E]
  const float* bdf  = (const float*)d_in[6];  // [E]
  const float* wfc  = (const float*)d_in[7];  // [E]
  // d_in[8] = b_fc: constant shift, cancels in softmax — unused.
  float* out = (float*)d_out;

  float* att2   = (float*)d_ws;                 // A*E = 0.5 MB
  float* Z      = att2 + (long)A_ * E_;         // A floats
  int*   counts = (int*)(Z + A_);               // 64 ints (adjacent to Z)
  int*   lists  = counts + 64;                  // S*A = 0.5 MB

  // zero Z + counts in one shot (adjacent), and out
  hipMemsetAsync(Z, 0, (A_ + 64) * sizeof(float), stream);
  hipMemsetAsync(out, 0, (size_t)out_size * sizeof(float), stream);

  att2s_kernel<<<A_ / 16,   256, 0, stream>>>(de, Wdf, bdf, sidx, att2,
                                              counts, lists);
  fused_kernel<<<S_ * NLCH, 256, 0, stream>>>(gs, Wsn, bsn, wfc, att2,
                                              counts, lists, out, Z);
  norm_kernel <<<(A_ * C_) / 256, 256, 0, stream>>>(out, Z);
}

// Round 8
// 151.121 us; speedup vs baseline: 1.0714x; 1.0714x over previous
//
#include <hip/hip_runtime.h>
#include <hip/hip_bf16.h>

#define S_ 64
#define P_ 2048
#define C_ 32
#define A_ 2048
#define D_ 128
#define E_ 64

#define LPX   128            // pixels per fused block
#define NLCH  (P_ / LPX)     // 16 chunks per scene

// ---------------------------------------------------------------------------
// att2[a,e] = de[a,:] @ W_df + b_df, plus scene scatter, plus out/Z zeroing
// (runs before fused_kernel on the stream; zeroing here kills one memset).
// ---------------------------------------------------------------------------
__global__ __launch_bounds__(256) void att2s_kernel(
    const float* __restrict__ de, const float* __restrict__ Wdf,
    const float* __restrict__ bdf, const int* __restrict__ sidx,
    float* __restrict__ att2, int* __restrict__ counts,
    int* __restrict__ lists, float* __restrict__ out, float* __restrict__ Z) {
  __shared__ float4 Wl[128 * 16];
  __shared__ float4 bl[16];
  __shared__ float  dl[16 * 128];
  const int tid = threadIdx.x;

  // zero out (16384 float4) and Z (512 float4) across the 128 blocks
  {
    const float4 z4 = make_float4(0.f, 0.f, 0.f, 0.f);
    const int gidx = blockIdx.x * 256 + tid;             // 0..32767
    if (gidx < (A_ * C_) / 4)      ((float4*)out)[gidx] = z4;
    else if (gidx < (A_ * C_) / 4 + A_ / 4)
      ((float4*)Z)[gidx - (A_ * C_) / 4] = z4;
  }

  // scatter this block's 16 agents (counts pre-zeroed by the memset)
  if (tid < 16) {
    const int a = blockIdx.x * 16 + tid;
    const int s = sidx[a];
    const int pos = atomicAdd(&counts[s], 1);
    lists[s * A_ + pos] = a;
  }

  const float4* W4 = (const float4*)Wdf;
#pragma unroll
  for (int i = 0; i < 8; ++i) Wl[tid + i * 256] = W4[tid + i * 256];
  if (tid < 16) bl[tid] = ((const float4*)bdf)[tid];
  const long base = (long)blockIdx.x * (16 * 128);
#pragma unroll
  for (int i = 0; i < 8; ++i) dl[tid + i * 256] = de[base + tid + i * 256];
  __syncthreads();

  const int r = tid >> 4, e4 = tid & 15;
  float4 acc = bl[e4];
#pragma unroll 4
  for (int d = 0; d < 128; ++d) {
    const float  g = dl[r * 128 + d];
    const float4 w = Wl[d * 16 + e4];
    acc.x = fmaf(g, w.x, acc.x);
    acc.y = fmaf(g, w.y, acc.y);
    acc.z = fmaf(g, w.z, acc.z);
    acc.w = fmaf(g, w.w, acc.w);
  }
  ((float4*)att2)[((long)blockIdx.x * 16 + r) * 16 + e4] = acc;
}

// ---------------------------------------------------------------------------
// Fused logits + unnormalized exp + pooling.
// Block = (scene, 128-px chunk). Phase 1 lane = (px = tid>>1, eh = tid&1):
// each lane owns 32 e's -> a1 = 8 float4. Per agent: 8 LDS b128 reads +
// 32 fmax/fma pairs + 1 shfl_xor; eh==0 writes exp(logit) to alpha_l
// (no max subtraction: |logit| <~ 10 since |w_fc| <= 1/8).
// Phase 2 lane = (j2 = tid>>3, c4 = tid&7): pool vs LDS-resident gs chunk.
// alpha_l rows padded to 132 floats (R7 had stride 64 -> 8-way conflicts).
// ---------------------------------------------------------------------------
__global__ __launch_bounds__(256) void fused_kernel(
    const float* __restrict__ gs, const float* __restrict__ Wsn,
    const float* __restrict__ bsn, const float* __restrict__ wfc,
    const float* __restrict__ att2, const int* __restrict__ counts,
    const int* __restrict__ lists, float* __restrict__ out,
    float* __restrict__ Z) {
  const int s   = blockIdx.x >> 4;
  const int p0  = (blockIdx.x & (NLCH - 1)) * LPX;
  const int tid = threadIdx.x;
  const int px  = tid >> 1;          // 0..127
  const int eh  = tid & 1;           // e-half (32 e's)

  __shared__ float  gsl[LPX][36];    // 18.4 KB; 144 B rows (16B-aligned)
  __shared__ float4 Wl4[32 * 16];    // 8 KB
  __shared__ float4 a2l[32][16];     // 2 KB
  __shared__ float  alpha_l[32][132];// 16.9 KB, padded stride
  __shared__ int    aidl[32];

  // stage W_sn (512 float4)
  const float4* W4 = (const float4*)Wsn;
  Wl4[tid]       = W4[tid];
  Wl4[tid + 256] = W4[tid + 256];

  // stage gs chunk: 128 px x 32 c = 1024 float4
  const float4* g4 = (const float4*)(gs + ((long)s * P_ + p0) * C_);
#pragma unroll
  for (int k = 0; k < 4; ++k) {
    const int f = tid + k * 256;
    const float4 v = g4[f];
    const int pp = f >> 3, c0 = (f & 7) * 4;
    gsl[pp][c0]     = v.x;
    gsl[pp][c0 + 1] = v.y;
    gsl[pp][c0 + 2] = v.z;
    gsl[pp][c0 + 3] = v.w;
  }

  // per-lane w_fc and bias-initialized att1 accumulator (32 e's each)
  const float4* wf4 = (const float4*)wfc;
  const float4* b4  = (const float4*)bsn;
  float4 wf[8], a1[8];
#pragma unroll
  for (int q = 0; q < 8; ++q) { wf[q] = wf4[eh * 8 + q]; a1[q] = b4[eh * 8 + q]; }
  __syncthreads();

  // att1 for (pixel px, this lane's 32 e's): 32c x 8 quads
#pragma unroll
  for (int c = 0; c < 32; ++c) {
    const float g = gsl[px][c];
#pragma unroll
    for (int q = 0; q < 8; ++q) {
      const float4 w = Wl4[c * 16 + eh * 8 + q];
      a1[q].x = fmaf(g, w.x, a1[q].x);
      a1[q].y = fmaf(g, w.y, a1[q].y);
      a1[q].z = fmaf(g, w.z, a1[q].z);
      a1[q].w = fmaf(g, w.w, a1[q].w);
    }
  }

  const int j2 = tid >> 3;           // phase-2 agent slot
  const int c4 = tid & 7;            // phase-2 channel quad
  const int n_s = counts[s];

  for (int g0 = 0; g0 < n_s; g0 += 32) {
    const int m = min(32, n_s - g0);
    __syncthreads();                 // prev group's a2l/alpha_l reads done
    if (tid < m) aidl[tid] = lists[s * A_ + g0 + tid];
    __syncthreads();
#pragma unroll
    for (int k = 0; k < 2; ++k) {
      const int idx = tid + k * 256; // 0..511
      const int j = idx >> 4, e4 = idx & 15;
      if (j < m) a2l[j][e4] = ((const float4*)att2)[aidl[j] * 16 + e4];
    }
    __syncthreads();

    // ---- phase 1: logits -> exp -> alpha_l ----
    for (int j = 0; j < m; ++j) {
      float c0 = 0.f, c1 = 0.f, c2 = 0.f, c3 = 0.f;
#pragma unroll
      for (int q = 0; q < 8; ++q) {
        const float4 t = a2l[j][eh * 8 + q];
        const float4 w = wf[q];
        const float4 av = a1[q];
        c0 = fmaf(fmaxf(av.x + t.x, 0.f), w.x, c0);
        c1 = fmaf(fmaxf(av.y + t.y, 0.f), w.y, c1);
        c2 = fmaf(fmaxf(av.z + t.z, 0.f), w.z, c2);
        c3 = fmaf(fmaxf(av.w + t.w, 0.f), w.w, c3);
      }
      float r = (c0 + c1) + (c2 + c3);
      r += __shfl_xor(r, 1);
      if (eh == 0) alpha_l[j][px] = __expf(r);
    }
    __syncthreads();

    // ---- phase 2: pool this group against LDS-resident gs chunk ----
    if (j2 < m) {
      const int a = aidl[j2];
      float4 a0 = make_float4(0.f, 0.f, 0.f, 0.f);
      float4 a1p = make_float4(0.f, 0.f, 0.f, 0.f);
      float4 a2p = make_float4(0.f, 0.f, 0.f, 0.f);
      float4 a3p = make_float4(0.f, 0.f, 0.f, 0.f);
      float  zs = 0.f;
#pragma unroll 4
      for (int p4 = 0; p4 < LPX / 4; ++p4) {
        const float w0 = alpha_l[j2][p4 * 4 + 0];
        const float w1 = alpha_l[j2][p4 * 4 + 1];
        const float w2 = alpha_l[j2][p4 * 4 + 2];
        const float w3 = alpha_l[j2][p4 * 4 + 3];
        const float4 v0 = *(const float4*)&gsl[p4 * 4 + 0][c4 * 4];
        const float4 v1 = *(const float4*)&gsl[p4 * 4 + 1][c4 * 4];
        const float4 v2 = *(const float4*)&gsl[p4 * 4 + 2][c4 * 4];
        const float4 v3 = *(const float4*)&gsl[p4 * 4 + 3][c4 * 4];
        zs += (w0 + w1) + (w2 + w3);
        a0.x = fmaf(w0, v0.x, a0.x); a0.y = fmaf(w0, v0.y, a0.y);
        a0.z = fmaf(w0, v0.z, a0.z); a0.w = fmaf(w0, v0.w, a0.w);
        a1p.x = fmaf(w1, v1.x, a1p.x); a1p.y = fmaf(w1, v1.y, a1p.y);
        a1p.z = fmaf(w1, v1.z, a1p.z); a1p.w = fmaf(w1, v1.w, a1p.w);
        a2p.x = fmaf(w2, v2.x, a2p.x); a2p.y = fmaf(w2, v2.y, a2p.y);
        a2p.z = fmaf(w2, v2.z, a2p.z); a2p.w = fmaf(w2, v2.w, a2p.w);
        a3p.x = fmaf(w3, v3.x, a3p.x); a3p.y = fmaf(w3, v3.y, a3p.y);
        a3p.z = fmaf(w3, v3.z, a3p.z); a3p.w = fmaf(w3, v3.w, a3p.w);
      }
      const float4 acc = make_float4((a0.x + a1p.x) + (a2p.x + a3p.x),
                                     (a0.y + a1p.y) + (a2p.y + a3p.y),
                                     (a0.z + a1p.z) + (a2p.z + a3p.z),
                                     (a0.w + a1p.w) + (a2p.w + a3p.w));
      float* op = out + (long)a * C_ + c4 * 4;
      atomicAdd(op,     acc.x);
      atomicAdd(op + 1, acc.y);
      atomicAdd(op + 2, acc.z);
      atomicAdd(op + 3, acc.w);
      if (c4 == 0) atomicAdd(&Z[a], zs);
    }
  }
}

// ---------------------------------------------------------------------------
// out[a,c] /= Z[a]
// ---------------------------------------------------------------------------
__global__ __launch_bounds__(256) void norm_kernel(
    float* __restrict__ out, const float* __restrict__ Z) {
  const int i = blockIdx.x * 256 + threadIdx.x;
  out[i] = out[i] / Z[i >> 5];
}

// ---------------------------------------------------------------------------
extern "C" void kernel_launch(void* const* d_in, const int* in_sizes, int n_in,
                              void* d_out, int out_size, void* d_ws, size_t ws_size,
                              hipStream_t stream) {
  const float* gs   = (const float*)d_in[0];  // [S,P,C]
  const int*   sidx = (const int*)  d_in[1];  // [A]
  const float* de   = (const float*)d_in[2];  // [A,D]
  const float* Wsn  = (const float*)d_in[3];  // [C,E]
  const float* bsn  = (const float*)d_in[4];  // [E]
  const float* Wdf  = (const float*)d_in[5];  // [D,E]
  const float* bdf  = (const float*)d_in[6];  // [E]
  const float* wfc  = (const float*)d_in[7];  // [E]
  // d_in[8] = b_fc: constant shift, cancels in softmax — unused.
  float* out = (float*)d_out;

  float* att2   = (float*)d_ws;                 // A*E = 0.5 MB
  float* Z      = att2 + (long)A_ * E_;         // A floats
  int*   counts = (int*)(Z + A_);               // 64 ints
  int*   lists  = counts + 64;                  // S*A = 0.5 MB

  hipMemsetAsync(counts, 0, 64 * sizeof(int), stream);   // only counts; out/Z
                                                          // zeroed in att2s
  att2s_kernel<<<A_ / 16,   256, 0, stream>>>(de, Wdf, bdf, sidx, att2,
                                              counts, lists, out, Z);
  fused_kernel<<<S_ * NLCH, 256, 0, stream>>>(gs, Wsn, bsn, wfc, att2,
                                              counts, lists, out, Z);
  norm_kernel <<<(A_ * C_) / 256, 256, 0, stream>>>(out, Z);
}

// Round 9
// 141.677 us; speedup vs baseline: 1.1428x; 1.0667x over previous
//
#include <hip/hip_runtime.h>
#include <hip/hip_bf16.h>

#define S_ 64
#define P_ 2048
#define C_ 32
#define A_ 2048
#define D_ 128
#define E_ 64

#define LPX   128            // pixels per fused block
#define NLCH  (P_ / LPX)     // 16 chunks per scene

// ---------------------------------------------------------------------------
// att2[a,e] = de[a,:] @ W_df + b_df, plus scene scatter, plus Z zeroing.
// ---------------------------------------------------------------------------
__global__ __launch_bounds__(256) void att2s_kernel(
    const float* __restrict__ de, const float* __restrict__ Wdf,
    const float* __restrict__ bdf, const int* __restrict__ sidx,
    float* __restrict__ att2, int* __restrict__ counts,
    int* __restrict__ lists, float* __restrict__ Z) {
  __shared__ float4 Wl[128 * 16];
  __shared__ float4 bl[16];
  __shared__ float  dl[16 * 128];
  const int tid = threadIdx.x;

  if (blockIdx.x == 0 && tid < A_ / 4)
    ((float4*)Z)[tid] = make_float4(0.f, 0.f, 0.f, 0.f);

  // scatter this block's 16 agents (counts pre-zeroed by the memset)
  if (tid < 16) {
    const int a = blockIdx.x * 16 + tid;
    const int s = sidx[a];
    const int pos = atomicAdd(&counts[s], 1);
    lists[s * A_ + pos] = a;
  }

  const float4* W4 = (const float4*)Wdf;
#pragma unroll
  for (int i = 0; i < 8; ++i) Wl[tid + i * 256] = W4[tid + i * 256];
  if (tid < 16) bl[tid] = ((const float4*)bdf)[tid];
  const long base = (long)blockIdx.x * (16 * 128);
#pragma unroll
  for (int i = 0; i < 8; ++i) dl[tid + i * 256] = de[base + tid + i * 256];
  __syncthreads();

  const int r = tid >> 4, e4 = tid & 15;
  float4 acc = bl[e4];
#pragma unroll 4
  for (int d = 0; d < 128; ++d) {
    const float  g = dl[r * 128 + d];
    const float4 w = Wl[d * 16 + e4];
    acc.x = fmaf(g, w.x, acc.x);
    acc.y = fmaf(g, w.y, acc.y);
    acc.z = fmaf(g, w.z, acc.z);
    acc.w = fmaf(g, w.w, acc.w);
  }
  ((float4*)att2)[((long)blockIdx.x * 16 + r) * 16 + e4] = acc;
}

// ---------------------------------------------------------------------------
// Fused logits + unnormalized exp + pooling.
// Block = (scene, 128-px chunk). Phase 1 lane = (px = tid>>1, eh = tid&1):
// 32 e's per lane. exp has no max subtraction (|logit| <~ 10, |w_fc|<=1/8).
// Phase 2 lane = (j2 = tid>>3, c4 = tid&7): pool vs LDS gs chunk, write
// per-chunk partials (no atomics on out). Z accumulated atomically (small).
// LDS: Wl4 unioned with alpha_l (Wl4 dead after att1 preamble) ->
// ~37.5 KB/block -> 4 blocks/CU.
// ---------------------------------------------------------------------------
__global__ __launch_bounds__(256) void fused_kernel(
    const float* __restrict__ gs, const float* __restrict__ Wsn,
    const float* __restrict__ bsn, const float* __restrict__ wfc,
    const float* __restrict__ att2, const int* __restrict__ counts,
    const int* __restrict__ lists, float* __restrict__ partial,
    float* __restrict__ Z) {
  const int s   = blockIdx.x >> 4;
  const int ch  = blockIdx.x & (NLCH - 1);
  const int p0  = ch * LPX;
  const int tid = threadIdx.x;
  const int px  = tid >> 1;          // 0..127
  const int eh  = tid & 1;           // e-half (32 e's)

  __shared__ float  gsl[LPX][36];    // 18.4 KB; 144 B rows (16B-aligned)
  __shared__ float  ubuf[32 * 132];  // 16.9 KB: Wl4 (preamble) / alpha_l (loop)
  __shared__ float4 a2l[32][16];     // 2 KB
  __shared__ int    aidl[32];

  float4* Wl4 = (float4*)ubuf;                       // 512 float4 used
  float (*alpha_l)[132] = (float(*)[132])ubuf;

  // stage W_sn (512 float4)
  const float4* W4 = (const float4*)Wsn;
  Wl4[tid]       = W4[tid];
  Wl4[tid + 256] = W4[tid + 256];

  // stage gs chunk: 128 px x 32 c = 1024 float4
  const float4* g4 = (const float4*)(gs + ((long)s * P_ + p0) * C_);
#pragma unroll
  for (int k = 0; k < 4; ++k) {
    const int f = tid + k * 256;
    const float4 v = g4[f];
    const int pp = f >> 3, c0 = (f & 7) * 4;
    gsl[pp][c0]     = v.x;
    gsl[pp][c0 + 1] = v.y;
    gsl[pp][c0 + 2] = v.z;
    gsl[pp][c0 + 3] = v.w;
  }

  // per-lane w_fc and bias-initialized att1 accumulator (32 e's each)
  const float4* wf4 = (const float4*)wfc;
  const float4* b4  = (const float4*)bsn;
  float4 wf[8], a1[8];
#pragma unroll
  for (int q = 0; q < 8; ++q) { wf[q] = wf4[eh * 8 + q]; a1[q] = b4[eh * 8 + q]; }
  __syncthreads();

  // att1 for (pixel px, this lane's 32 e's): reads Wl4 (= ubuf) last time
#pragma unroll
  for (int c = 0; c < 32; ++c) {
    const float g = gsl[px][c];
#pragma unroll
    for (int q = 0; q < 8; ++q) {
      const float4 w = Wl4[c * 16 + eh * 8 + q];
      a1[q].x = fmaf(g, w.x, a1[q].x);
      a1[q].y = fmaf(g, w.y, a1[q].y);
      a1[q].z = fmaf(g, w.z, a1[q].z);
      a1[q].w = fmaf(g, w.w, a1[q].w);
    }
  }

  const int j2 = tid >> 3;           // phase-2 agent slot
  const int c4 = tid & 7;            // phase-2 channel quad
  const int n_s = counts[s];

  for (int g0 = 0; g0 < n_s; g0 += 32) {
    const int m = min(32, n_s - g0);
    __syncthreads();                 // prev alpha/a2l reads done; att1's
                                     // ubuf reads done (first iteration)
    // stage a2l + aidl straight from lists/att2 (one barrier)
#pragma unroll
    for (int k = 0; k < 2; ++k) {
      const int idx = tid + k * 256; // 0..511
      const int j = idx >> 4, e4 = idx & 15;
      if (j < m) {
        const int aj = lists[s * A_ + g0 + j];
        a2l[j][e4] = ((const float4*)att2)[aj * 16 + e4];
        if (e4 == 0) aidl[j] = aj;
      }
    }
    __syncthreads();

    // ---- phase 1: logits -> exp -> alpha_l ----
    for (int j = 0; j < m; ++j) {
      float c0 = 0.f, c1 = 0.f, c2 = 0.f, c3 = 0.f;
#pragma unroll
      for (int q = 0; q < 8; ++q) {
        const float4 t = a2l[j][eh * 8 + q];
        const float4 w = wf[q];
        const float4 av = a1[q];
        c0 = fmaf(fmaxf(av.x + t.x, 0.f), w.x, c0);
        c1 = fmaf(fmaxf(av.y + t.y, 0.f), w.y, c1);
        c2 = fmaf(fmaxf(av.z + t.z, 0.f), w.z, c2);
        c3 = fmaf(fmaxf(av.w + t.w, 0.f), w.w, c3);
      }
      float r = (c0 + c1) + (c2 + c3);
      r += __shfl_xor(r, 1);
      if (eh == 0) alpha_l[j][px] = __expf(r);
    }
    __syncthreads();

    // ---- phase 2: pool this group against LDS-resident gs chunk ----
    if (j2 < m) {
      const int a = aidl[j2];
      float4 a0 = make_float4(0.f, 0.f, 0.f, 0.f);
      float4 a1p = make_float4(0.f, 0.f, 0.f, 0.f);
      float4 a2p = make_float4(0.f, 0.f, 0.f, 0.f);
      float4 a3p = make_float4(0.f, 0.f, 0.f, 0.f);
      float  zs = 0.f;
#pragma unroll 4
      for (int p4 = 0; p4 < LPX / 4; ++p4) {
        const float w0 = alpha_l[j2][p4 * 4 + 0];
        const float w1 = alpha_l[j2][p4 * 4 + 1];
        const float w2 = alpha_l[j2][p4 * 4 + 2];
        const float w3 = alpha_l[j2][p4 * 4 + 3];
        const float4 v0 = *(const float4*)&gsl[p4 * 4 + 0][c4 * 4];
        const float4 v1 = *(const float4*)&gsl[p4 * 4 + 1][c4 * 4];
        const float4 v2 = *(const float4*)&gsl[p4 * 4 + 2][c4 * 4];
        const float4 v3 = *(const float4*)&gsl[p4 * 4 + 3][c4 * 4];
        zs += (w0 + w1) + (w2 + w3);
        a0.x = fmaf(w0, v0.x, a0.x); a0.y = fmaf(w0, v0.y, a0.y);
        a0.z = fmaf(w0, v0.z, a0.z); a0.w = fmaf(w0, v0.w, a0.w);
        a1p.x = fmaf(w1, v1.x, a1p.x); a1p.y = fmaf(w1, v1.y, a1p.y);
        a1p.z = fmaf(w1, v1.z, a1p.z); a1p.w = fmaf(w1, v1.w, a1p.w);
        a2p.x = fmaf(w2, v2.x, a2p.x); a2p.y = fmaf(w2, v2.y, a2p.y);
        a2p.z = fmaf(w2, v2.z, a2p.z); a2p.w = fmaf(w2, v2.w, a2p.w);
        a3p.x = fmaf(w3, v3.x, a3p.x); a3p.y = fmaf(w3, v3.y, a3p.y);
        a3p.z = fmaf(w3, v3.z, a3p.z); a3p.w = fmaf(w3, v3.w, a3p.w);
      }
      const float4 acc = make_float4((a0.x + a1p.x) + (a2p.x + a3p.x),
                                     (a0.y + a1p.y) + (a2p.y + a3p.y),
                                     (a0.z + a1p.z) + (a2p.z + a3p.z),
                                     (a0.w + a1p.w) + (a2p.w + a3p.w));
      *(float4*)(partial + (long)ch * (A_ * C_) + (long)a * C_ + c4 * 4) = acc;
      if (c4 == 0) atomicAdd(&Z[a], zs);
    }
  }
}

// ---------------------------------------------------------------------------
// out[a,c] = (sum_ch partial[ch][a][c]) / Z[a]
// ---------------------------------------------------------------------------
__global__ __launch_bounds__(256) void norm_kernel(
    const float* __restrict__ partial, const float* __restrict__ Z,
    float* __restrict__ out) {
  const int i = blockIdx.x * 256 + threadIdx.x;   // a*C + c
  float sum = 0.f;
#pragma unroll
  for (int ch = 0; ch < NLCH; ++ch) sum += partial[(long)ch * (A_ * C_) + i];
  out[i] = sum / Z[i >> 5];
}

// ---------------------------------------------------------------------------
extern "C" void kernel_launch(void* const* d_in, const int* in_sizes, int n_in,
                              void* d_out, int out_size, void* d_ws, size_t ws_size,
                              hipStream_t stream) {
  const float* gs   = (const float*)d_in[0];  // [S,P,C]
  const int*   sidx = (const int*)  d_in[1];  // [A]
  const float* de   = (const float*)d_in[2];  // [A,D]
  const float* Wsn  = (const float*)d_in[3];  // [C,E]
  const float* bsn  = (const float*)d_in[4];  // [E]
  const float* Wdf  = (const float*)d_in[5];  // [D,E]
  const float* bdf  = (const float*)d_in[6];  // [E]
  const float* wfc  = (const float*)d_in[7];  // [E]
  // d_in[8] = b_fc: constant shift, cancels in softmax — unused.
  float* out = (float*)d_out;

  float* att2    = (float*)d_ws;                    // A*E        = 0.5 MB
  float* Z       = att2 + (long)A_ * E_;            // A floats
  int*   counts  = (int*)(Z + A_);                  // 64 ints
  int*   lists   = counts + 64;                     // S*A        = 0.5 MB
  float* partial = (float*)(lists + (long)S_ * A_); // NLCH*A*C   = 4 MB

  hipMemsetAsync(counts, 0, 64 * sizeof(int), stream);
  att2s_kernel<<<A_ / 16,   256, 0, stream>>>(de, Wdf, bdf, sidx, att2,
                                              counts, lists, Z);
  fused_kernel<<<S_ * NLCH, 256, 0, stream>>>(gs, Wsn, bsn, wfc, att2,
                                              counts, lists, partial, Z);
  norm_kernel <<<(A_ * C_) / 256, 256, 0, stream>>>(partial, Z, out);
}